// Round 10
// baseline (3808.130 us; speedup 1.0000x reference)
//
#include <hip/hip_runtime.h>
#include <cstdint>
#include <cstddef>

#define BB 64
#define HH 168
#define NN 512
#define FF 8
#define UL 128   // lstm units
#define GD 512   // gate dim (4*UL)

__device__ __forceinline__ float frcp(float x){ return __builtin_amdgcn_rcpf(x); }

// ======================================================================
// k_big: blocks 0-63 = LSTM1 (R3-validated core), blocks 64-127 = full
// per-batch GCN chain (sum -> moments -> gcn1 -> gcn2 -> conv) in LDS.
// __launch_bounds__(512,2): the validated-safe codegen pair (R3: VGPR 84,
// no scratch). LDS union: t_s[16384] | adj_s[8704] | aux[8192] floats.
// ======================================================================
__global__ __launch_bounds__(512,2) void k_big(const float* __restrict__ in,
      const float* __restrict__ k1, const float* __restrict__ rk1, const float* __restrict__ bl1,
      float* __restrict__ l1,
      const float* __restrict__ adj,
      const float* __restrict__ w1, const float* __restrict__ b1g,
      const float* __restrict__ w2, const float* __restrict__ b2g,
      const float* __restrict__ wc1, const float* __restrict__ bc1,
      const float* __restrict__ wc2, const float* __restrict__ bc2,
      float* __restrict__ feat){
  __shared__ float L[33280];          // 133120 B
  float* t_s   = L;                   // 16384 fl : t / h1 / g
  float* adj_s = L + 16384;           // 8704 fl  : adj tiles / conv w1
  float* aux   = L + 25088;           // 8192 fl  : nf / t2 / conv partials
  int tid = threadIdx.x;

  if(blockIdx.x >= 64){
    // ================= GCN chain for batch b =================
    int b = blockIdx.x - 64;
    // ---- phase S: moments over H for node n = tid ----
    {
      int n = tid;
      const float* p = in + ((size_t)b*HH*NN + n)*FF;
      float s1=0.f,s2=0.f,s3=0.f,s4=0.f,st=0.f,s1h=0.f,s2h=0.f;
      #pragma unroll 4
      for(int h=0;h<HH;++h){
        float x = p[(size_t)h*NN*FF];
        float hc = (float)h - 83.5f;
        s1 += x;
        float x2 = x*x;
        s2 += x2; s3 += x2*x; s4 += x2*x2; st += hc*x;
        if(h>=84){ s1h += x; s2h += x2; }
      }
      const float iH = 1.0f/168.0f, iHh = 1.0f/84.0f;
      float mean = s1*iH, meanh = s1h*iHh;
      float ex2 = s2*iH, ex3 = s3*iH, ex4 = s4*iH;
      float m2 = ex2 - mean*mean;
      float m3 = ex3 - 3.0f*mean*ex2 + 2.0f*mean*mean*mean;
      float m4 = ex4 - 4.0f*mean*ex3 + 6.0f*mean*mean*ex2 - 3.0f*mean*mean*mean*mean;
      m2 = fmaxf(m2, 0.0f);
      float stdf = sqrtf(m2);
      float m2h = fmaxf(s2h*iHh - meanh*meanh, 0.0f);
      float stdh = sqrtf(m2h);
      float denom = m2*stdf;
      float skew = denom > 0.0f ? m3/denom : 0.0f;
      float kurt = m2 > 0.0f ? (m4/(m2*m2) - 3.0f) : 0.0f;
      float slope = st * (1.0f/395122.0f);
      float* o = aux + n*7;
      o[0]=mean; o[1]=meanh; o[2]=stdf; o[3]=stdh; o[4]=skew; o[5]=kurt; o[6]=slope;
    }
    __syncthreads();
    // ---- phase G1 stage: t_s[m*32+c] = nf[m] @ w1[:,c] ----
    {
      int c = tid&31;
      float w1c[7];
      #pragma unroll
      for(int k=0;k<7;++k) w1c[k] = w1[k*32+c];
      for(int m=tid>>5; m<NN; m+=16){
        float a = 0.f;
        #pragma unroll
        for(int k=0;k<7;++k) a += aux[m*7+k]*w1c[k];
        t_s[m*32+c] = a;
      }
    }
    __syncthreads();
    // ---- phase G1 main: h1 = relu(adj @ t) ----
    int c = tid&31, nl = tid>>5;
    float accg[4][8];
    #pragma unroll
    for(int nt=0;nt<4;++nt)
      #pragma unroll
      for(int j=0;j<8;++j) accg[nt][j]=0.f;
    for(int nt=0; nt<4; ++nt){
      int n0 = nt*128;
      for(int mt=0; mt<8; ++mt){
        __syncthreads();
        for(int idx=tid; idx<128*64; idx+=512){
          int r = idx>>6, cc = idx&63;
          adj_s[r*68+cc] = adj[(size_t)(n0+r)*NN + mt*64 + cc];
        }
        __syncthreads();
        for(int mm=0; mm<64; mm+=4){
          float tv0 = t_s[(mt*64+mm+0)*32 + c];
          float tv1 = t_s[(mt*64+mm+1)*32 + c];
          float tv2 = t_s[(mt*64+mm+2)*32 + c];
          float tv3 = t_s[(mt*64+mm+3)*32 + c];
          #pragma unroll
          for(int j=0;j<8;++j){
            float4 a4 = *(const float4*)&adj_s[(nl+16*j)*68 + mm];
            accg[nt][j] += a4.x*tv0 + a4.y*tv1 + a4.z*tv2 + a4.w*tv3;
          }
        }
      }
    }
    __syncthreads();     // all t_s reads done
    {
      float bb = b1g[c];
      #pragma unroll
      for(int nt=0;nt<4;++nt)
        #pragma unroll
        for(int j=0;j<8;++j){
          int n = nt*128 + nl + 16*j;
          t_s[n*32 + c] = fmaxf(accg[nt][j]+bb, 0.0f);   // h1 into t_s
        }
    }
    __syncthreads();
    // ---- phase G2 stage: aux[m*16+j2] = h1[m] @ w2[:,j2] ----
    {
      int j2 = tid&15;
      float w2c[32];
      #pragma unroll
      for(int cc=0;cc<32;++cc) w2c[cc] = w2[cc*16+j2];
      for(int m=tid>>4; m<NN; m+=32){
        float a = 0.f;
        #pragma unroll
        for(int cc=0;cc<32;++cc) a += t_s[m*32+cc]*w2c[cc];
        aux[m*16+j2] = a;
      }
    }
    __syncthreads();
    // ---- phase G2 main: g = relu(adj @ t2) ----
    int j = tid&15, nl2 = tid>>4;      // nl2 0..31
    float acc2[16];
    #pragma unroll
    for(int q=0;q<16;++q) acc2[q]=0.f;
    for(int nt=0; nt<4; ++nt){
      int n0 = nt*128;
      for(int mt=0; mt<8; ++mt){
        __syncthreads();
        for(int idx=tid; idx<128*64; idx+=512){
          int r = idx>>6, cc = idx&63;
          adj_s[r*68+cc] = adj[(size_t)(n0+r)*NN + mt*64 + cc];
        }
        __syncthreads();
        for(int mm=0; mm<64; mm+=4){
          float tv0 = aux[(mt*64+mm+0)*16 + j];
          float tv1 = aux[(mt*64+mm+1)*16 + j];
          float tv2 = aux[(mt*64+mm+2)*16 + j];
          float tv3 = aux[(mt*64+mm+3)*16 + j];
          #pragma unroll
          for(int qq=0;qq<4;++qq){
            float4 a4 = *(const float4*)&adj_s[(nl2+32*qq)*68 + mm];
            acc2[nt*4+qq] += a4.x*tv0 + a4.y*tv1 + a4.z*tv2 + a4.w*tv3;
          }
        }
      }
    }
    __syncthreads();
    {
      float bb2 = b2g[j];
      #pragma unroll
      for(int nt=0;nt<4;++nt)
        #pragma unroll
        for(int qq=0;qq<4;++qq){
          int n = nt*128 + nl2 + 32*qq;
          t_s[n*16 + j] = fmaxf(acc2[nt*4+qq]+bb2, 0.0f);   // g into t_s
        }
    }
    __syncthreads();
    // ---- phase conv: c1 -> pool -> c2 -> feat[b,0:64) ----
    for(int idx=tid; idx<3*NN*4; idx+=512) adj_s[idx] = wc1[idx];
    __syncthreads();
    {
      int q = tid>>6, pp = tid&63, o = pp>>4, x = pp&15;
      int c0 = q*64;
      float a = 0.f;
      #pragma unroll
      for(int k=0;k<3;++k){
        int xx = x + k - 1;
        if(xx>=0 && xx<16){
          #pragma unroll 4
          for(int cc=c0; cc<c0+64; ++cc) a += t_s[cc*16+xx]*adj_s[(k*NN+cc)*4+o];
        }
      }
      aux[(q*4+o)*16 + x] = a;   // c1 partials: 8 splits
    }
    __syncthreads();
    if(tid<64){
      int o = tid>>4, x = tid&15;
      float s = bc1[o];
      #pragma unroll
      for(int q=0;q<8;++q) s += aux[(q*4+o)*16 + x];
      aux[512 + o*16 + x] = s;
    }
    __syncthreads();
    if(tid<32){
      int oo = tid>>3, xp = tid&7;
      float pv = 0.5f*(aux[512+oo*16+2*xp] + aux[512+oo*16+2*xp+1]);
      aux[576 + oo*8 + xp] = pv;
      feat[b*192 + 32 + oo*8 + xp] = pv;
    }
    __syncthreads();
    if(tid<32){
      int oo = tid>>3, x2 = tid&7;
      float a2 = bc2[oo];
      #pragma unroll
      for(int k=0;k<3;++k){
        int xx = x2 + k - 1;
        if(xx>=0 && xx<8){
          #pragma unroll
          for(int c4=0;c4<4;++c4) a2 += aux[576 + c4*8 + xx]*wc2[(k*4+c4)*4+oo];
        }
      }
      feat[b*192 + oo*8 + x2] = a2;
    }
    return;
  }

  // ================= LSTM1 (R3-validated core, verbatim) =================
  float* seq_s = L;             // 1344 fl
  float* h_s2  = L + 1344;      // 4*36 fl
  float* a_s   = L + 1492;      // 512 fl
  int b = blockIdx.x;
  int q = tid&3, grp = tid>>2;
  bool q0 = (tid&1)!=0, q1 = (tid&2)!=0;
  float4 w4[32];
  {
    const float4* rkp = (const float4*)rk1;
    #pragma unroll
    for(int k=0;k<32;++k) w4[k] = rkp[(size_t)(q*32+k)*(GD/4) + grp];
  }
  float wkx[FF];
  #pragma unroll
  for(int f=0;f<FF;++f) wkx[f] = k1[f*GD+tid];
  float bz = bl1[tid];
  bool isg = ((tid>>7)==2);
  float Ac = isg?1.f:0.f, Bc = isg?-2.f:1.f, Sc = isg?2.f:-1.f;
  for(int idx=tid; idx<HH*FF; idx+=512)
    seq_s[idx] = in[(size_t)(b*HH + (idx>>3))*NN*FF + (idx&7)];
  if(tid<UL) h_s2[(tid>>5)*36 + (tid&31)] = 0.0f;
  float c = 0.0f;
  __syncthreads();
  const float4* hq = (const float4*)&h_s2[q*36];
  #pragma unroll 1
  for(int t=0;t<HH;++t){
    float4 x0 = *(const float4*)&seq_s[t*FF];
    float4 x1 = *(const float4*)&seq_s[t*FF+4];
    float zx = bz + x0.x*wkx[0]+x0.y*wkx[1]+x0.z*wkx[2]+x0.w*wkx[3]
                  + x1.x*wkx[4]+x1.y*wkx[5]+x1.z*wkx[6]+x1.w*wkx[7];
    float p0=0.f,p1=0.f,p2=0.f,p3=0.f;
    #pragma unroll
    for(int jj=0;jj<8;++jj){
      float4 hv = hq[jj];
      p0 += hv.x*w4[4*jj].x + hv.y*w4[4*jj+1].x + hv.z*w4[4*jj+2].x + hv.w*w4[4*jj+3].x;
      p1 += hv.x*w4[4*jj].y + hv.y*w4[4*jj+1].y + hv.z*w4[4*jj+2].y + hv.w*w4[4*jj+3].y;
      p2 += hv.x*w4[4*jj].z + hv.y*w4[4*jj+1].z + hv.z*w4[4*jj+2].z + hv.w*w4[4*jj+3].z;
      p3 += hv.x*w4[4*jj].w + hv.y*w4[4*jj+1].w + hv.z*w4[4*jj+2].w + hv.w*w4[4*jj+3].w;
    }
    float send0 = q0 ? p0 : p1;
    float send1 = q0 ? p2 : p3;
    float r0 = __shfl_xor(send0, 1);
    float r1 = __shfl_xor(send1, 1);
    float s0 = (q0 ? p1 : p0) + r0;
    float s1v = (q0 ? p3 : p2) + r1;
    float send2 = q1 ? s0 : s1v;
    float r2 = __shfl_xor(send2, 2);
    float z = zx + (q1 ? s1v : s0) + r2;
    float act = Ac + Bc*frcp(1.0f + __expf(Sc*z));
    a_s[tid] = act;
    __syncthreads();
    int u = tid&127;
    float ia=a_s[u], fa=a_s[UL+u], ga=a_s[2*UL+u], oa=a_s[3*UL+u];
    c = fa*c + ia*ga;
    float th = 1.0f - 2.0f*frcp(1.0f + __expf(2.0f*c));
    float hn = oa*th;
    if(tid<UL){
      h_s2[(tid>>5)*36 + (tid&31)] = hn;
      l1[((size_t)b*HH + t)*UL + tid] = hn;
    }
    __syncthreads();
  }
}

// ==================== zin2 = l1 @ k2 + b2 (R8-validated) ====================
__global__ __launch_bounds__(256) void k_zin2(const float* __restrict__ l1, const float* __restrict__ k2,
        const float* __restrict__ b2, float* __restrict__ zin){
  __shared__ float l_s[21*UL];
  int b = blockIdx.x>>3, t0 = (blockIdx.x&7)*21;
  int tid = threadIdx.x;
  for(int idx=tid; idx<21*UL; idx+=256)
    l_s[idx] = l1[((size_t)b*HH + t0 + (idx>>7))*UL + (idx&127)];
  __syncthreads();
  float acc0[21], acc1[21];
  #pragma unroll
  for(int q=0;q<21;++q){acc0[q]=0.f;acc1[q]=0.f;}
  for(int j=0;j<UL;j+=4){
    float kv00=k2[j*GD+tid],     kv01=k2[(j+1)*GD+tid],     kv02=k2[(j+2)*GD+tid],     kv03=k2[(j+3)*GD+tid];
    float kv10=k2[j*GD+tid+256], kv11=k2[(j+1)*GD+tid+256], kv12=k2[(j+2)*GD+tid+256], kv13=k2[(j+3)*GD+tid+256];
    #pragma unroll
    for(int q=0;q<21;++q){
      float4 lv = *(const float4*)&l_s[q*UL + j];
      acc0[q] += lv.x*kv00 + lv.y*kv01 + lv.z*kv02 + lv.w*kv03;
      acc1[q] += lv.x*kv10 + lv.y*kv11 + lv.z*kv12 + lv.w*kv13;
    }
  }
  float bb0 = b2[tid], bb1 = b2[tid+256];
  #pragma unroll
  for(int q=0;q<21;++q){
    zin[((size_t)b*HH + t0 + q)*GD + tid]       = acc0[q] + bb0;
    zin[((size_t)b*HH + t0 + q)*GD + tid + 256] = acc1[q] + bb1;
  }
}

// ==================== LSTM2 (R3-validated core) + folded k_out ====================
__global__ __launch_bounds__(512,2) void k_rec2(const float* __restrict__ zin, const float* __restrict__ rk2,
        const float* __restrict__ feat, const float* __restrict__ wo, const float* __restrict__ bo,
        float* __restrict__ out){
  __shared__ float h_s2[4*36];
  __shared__ float a_s[GD];
  int b = blockIdx.x, tid = threadIdx.x;
  int q = tid&3, grp = tid>>2;
  bool q0 = (tid&1)!=0, q1 = (tid&2)!=0;
  float4 w4[32];
  {
    const float4* rkp = (const float4*)rk2;
    #pragma unroll
    for(int k=0;k<32;++k) w4[k] = rkp[(size_t)(q*32+k)*(GD/4) + grp];
  }
  bool isg = ((tid>>7)==2);
  float Ac = isg?1.f:0.f, Bc = isg?-2.f:1.f, Sc = isg?2.f:-1.f;
  if(tid<UL) h_s2[(tid>>5)*36 + (tid&31)] = 0.0f;
  float c = 0.0f;
  float zc = zin[(size_t)b*HH*GD + tid];
  __syncthreads();
  const float4* hq = (const float4*)&h_s2[q*36];
  #pragma unroll 1
  for(int t=0;t<HH;++t){
    float nz = 0.f;
    if(t+1<HH) nz = zin[((size_t)b*HH + t+1)*GD + tid];
    float p0=0.f,p1=0.f,p2=0.f,p3=0.f;
    #pragma unroll
    for(int jj=0;jj<8;++jj){
      float4 hv = hq[jj];
      p0 += hv.x*w4[4*jj].x + hv.y*w4[4*jj+1].x + hv.z*w4[4*jj+2].x + hv.w*w4[4*jj+3].x;
      p1 += hv.x*w4[4*jj].y + hv.y*w4[4*jj+1].y + hv.z*w4[4*jj+2].y + hv.w*w4[4*jj+3].y;
      p2 += hv.x*w4[4*jj].z + hv.y*w4[4*jj+1].z + hv.z*w4[4*jj+2].z + hv.w*w4[4*jj+3].z;
      p3 += hv.x*w4[4*jj].w + hv.y*w4[4*jj+1].w + hv.z*w4[4*jj+2].w + hv.w*w4[4*jj+3].w;
    }
    float send0 = q0 ? p0 : p1;
    float send1 = q0 ? p2 : p3;
    float r0 = __shfl_xor(send0, 1);
    float r1 = __shfl_xor(send1, 1);
    float s0 = (q0 ? p1 : p0) + r0;
    float s1v = (q0 ? p3 : p2) + r1;
    float send2 = q1 ? s0 : s1v;
    float r2 = __shfl_xor(send2, 2);
    float z = zc + (q1 ? s1v : s0) + r2;
    float act = Ac + Bc*frcp(1.0f + __expf(Sc*z));
    a_s[tid] = act;
    __syncthreads();
    int u = tid&127;
    float ia=a_s[u], fa=a_s[UL+u], ga=a_s[2*UL+u], oa=a_s[3*UL+u];
    c = fa*c + ia*ga;
    float th = 1.0f - 2.0f*frcp(1.0f + __expf(2.0f*c));
    float hn = oa*th;
    if(tid<UL) h_s2[(tid>>5)*36 + (tid&31)] = hn;
    __syncthreads();
    zc = nz;
  }
  // folded k_out: out[b,p] = [conv_feat(64) | lstm2_h(128)] @ wo + bo
  if(tid<24){
    int p = tid;
    float a = bo[p];
    const float* f = feat + (size_t)b*192;
    for(int k=0;k<64;++k)  a += f[k]*wo[k*24+p];
    for(int u2=0;u2<UL;++u2) a += h_s2[(u2>>5)*36 + (u2&31)]*wo[(64+u2)*24+p];
    out[b*24+p] = a;
  }
}

extern "C" void kernel_launch(void* const* d_in, const int* in_sizes, int n_in,
                              void* d_out, int out_size, void* d_ws, size_t ws_size,
                              hipStream_t stream){
  const float* inp = (const float*)d_in[0];
  const float* adj = (const float*)d_in[1];
  const float* w1  = (const float*)d_in[2];
  const float* b1  = (const float*)d_in[3];
  const float* w2  = (const float*)d_in[4];
  const float* b2  = (const float*)d_in[5];
  const float* wc1 = (const float*)d_in[6];
  const float* bc1 = (const float*)d_in[7];
  const float* wc2 = (const float*)d_in[8];
  const float* bc2 = (const float*)d_in[9];
  const float* k1  = (const float*)d_in[10];
  const float* rk1 = (const float*)d_in[11];
  const float* bl1 = (const float*)d_in[12];
  const float* k2  = (const float*)d_in[13];
  const float* rk2 = (const float*)d_in[14];
  const float* bl2 = (const float*)d_in[15];
  const float* wo  = (const float*)d_in[16];
  const float* bo  = (const float*)d_in[17];
  float* out = (float*)d_out;
  float* ws = (float*)d_ws;

  float* feat = ws;                 // 12288
  float* l1   = feat + 12288;       // 1376256
  float* zin  = l1 + 1376256;       // 5505024

  k_big <<<dim3(128), dim3(512), 0, stream>>>(inp, k1, rk1, bl1, l1,
                                              adj, w1, b1, w2, b2, wc1, bc1, wc2, bc2, feat);
  k_zin2<<<dim3(512), dim3(256), 0, stream>>>(l1, k2, bl2, zin);
  k_rec2<<<dim3(64),  dim3(512), 0, stream>>>(zin, rk2, feat, wo, bo, out);
}

// Round 11
// 468.239 us; speedup vs baseline: 8.1329x; 8.1329x over previous
//
#include <hip/hip_runtime.h>
#include <cstdint>
#include <cstddef>

#define BB 64
#define HH 168
#define NN 512
#define FF 8
#define UL 128   // lstm units
#define GD 512   // gate dim (4*UL)

__device__ __forceinline__ float frcp(float x){ return __builtin_amdgcn_rcpf(x); }

// ---------------- summaries: partial sums over half the H axis ----------------
__global__ __launch_bounds__(256) void k_sum(const float* __restrict__ in, float* __restrict__ ps){
  int bid = blockIdx.x;
  int b = bid>>2, nh = (bid>>1)&1, hh = bid&1;
  int n = nh*256 + threadIdx.x;
  int h0 = hh*84;
  const float* p = in + ((size_t)(b*HH + h0)*NN + n)*FF;
  float s1=0.f,s2=0.f,s3=0.f,s4=0.f,st=0.f;
  #pragma unroll 4
  for(int h=0;h<84;++h){
    float x = p[(size_t)h*NN*FF];
    float hc = (float)(h+h0) - 83.5f;
    s1 += x;
    float x2 = x*x;
    s2 += x2;
    s3 += x2*x;
    s4 += x2*x2;
    st += hc*x;
  }
  float* o = ps + ((size_t)((b*NN+n)*2 + hh))*8;
  o[0]=s1; o[1]=s2; o[2]=s3; o[3]=s4; o[4]=st;
}

__global__ __launch_bounds__(256) void k_sumc(const float* __restrict__ ps, float* __restrict__ nf){
  int idx = blockIdx.x*256 + threadIdx.x;
  const float* a = ps + (size_t)idx*16;
  const float* c2 = a + 8;
  float s1 = a[0]+c2[0], s2 = a[1]+c2[1], s3 = a[2]+c2[2], s4 = a[3]+c2[3], st = a[4]+c2[4];
  float s1h = c2[0], s2h = c2[1];
  const float iH = 1.0f/168.0f, iHh = 1.0f/84.0f;
  float mean = s1*iH, meanh = s1h*iHh;
  float ex2 = s2*iH, ex3 = s3*iH, ex4 = s4*iH;
  float m2 = ex2 - mean*mean;
  float m3 = ex3 - 3.0f*mean*ex2 + 2.0f*mean*mean*mean;
  float m4 = ex4 - 4.0f*mean*ex3 + 6.0f*mean*mean*ex2 - 3.0f*mean*mean*mean*mean;
  m2 = fmaxf(m2, 0.0f);
  float stdf = sqrtf(m2);
  float m2h = fmaxf(s2h*iHh - meanh*meanh, 0.0f);
  float stdh = sqrtf(m2h);
  float denom = m2*stdf;
  float skew = denom > 0.0f ? m3/denom : 0.0f;
  float kurt = m2 > 0.0f ? (m4/(m2*m2) - 3.0f) : 0.0f;
  float slope = st * (1.0f/395122.0f);
  float* o = nf + (size_t)idx*7;
  o[0]=mean; o[1]=meanh; o[2]=stdf; o[3]=stdh; o[4]=skew; o[5]=kurt; o[6]=slope;
}

// ---------------- GCN layer 1 ----------------
__global__ __launch_bounds__(256) void k_gcn1(const float* __restrict__ nf, const float* __restrict__ adj,
        const float* __restrict__ w1, const float* __restrict__ b1, float* __restrict__ h1){
  __shared__ float t_s[NN*32];
  __shared__ float adj_s[128*68];
  int b = blockIdx.x>>2, n0 = (blockIdx.x&3)*128;
  int tid = threadIdx.x;
  {
    int c = tid&31;
    float w1c[7];
    #pragma unroll
    for(int k=0;k<7;++k) w1c[k] = w1[k*32+c];
    for(int idx=tid; idx<NN*32; idx+=256){
      int m = idx>>5;
      const float* nfp = nf + (size_t)(b*NN+m)*7;
      float acc = 0.f;
      #pragma unroll
      for(int k=0;k<7;++k) acc += nfp[k]*w1c[k];
      t_s[idx] = acc;
    }
  }
  int c2 = tid&15, nl = tid>>4;
  float acc[8][2];
  #pragma unroll
  for(int j=0;j<8;++j){acc[j][0]=0.f;acc[j][1]=0.f;}
  for(int mt=0; mt<8; ++mt){
    __syncthreads();
    for(int idx=tid; idx<128*64; idx+=256){
      int r = idx>>6, cc = idx&63;
      adj_s[r*68+cc] = adj[(size_t)(n0+r)*NN + mt*64 + cc];
    }
    __syncthreads();
    for(int mm=0; mm<64; mm+=4){
      float2 tv[4];
      #pragma unroll
      for(int q=0;q<4;++q) tv[q] = *(const float2*)&t_s[(mt*64+mm+q)*32 + 2*c2];
      #pragma unroll
      for(int j=0;j<8;++j){
        float4 a4 = *(const float4*)&adj_s[(nl+16*j)*68 + mm];
        acc[j][0] += a4.x*tv[0].x + a4.y*tv[1].x + a4.z*tv[2].x + a4.w*tv[3].x;
        acc[j][1] += a4.x*tv[0].y + a4.y*tv[1].y + a4.z*tv[2].y + a4.w*tv[3].y;
      }
    }
  }
  float bb0 = b1[2*c2], bb1 = b1[2*c2+1];
  #pragma unroll
  for(int j=0;j<8;++j){
    int n = n0 + nl + 16*j;
    float2 v;
    v.x = fmaxf(acc[j][0]+bb0, 0.0f);
    v.y = fmaxf(acc[j][1]+bb1, 0.0f);
    *(float2*)&h1[(size_t)(b*NN+n)*32 + 2*c2] = v;
  }
}

// ---------------- GCN layer 2 ----------------
__global__ __launch_bounds__(256) void k_gcn2(const float* __restrict__ h1, const float* __restrict__ adj,
        const float* __restrict__ w2, const float* __restrict__ b2, float* __restrict__ g){
  __shared__ float t_s[NN*16];
  __shared__ float adj_s[128*68];
  int b = blockIdx.x>>2, n0 = (blockIdx.x&3)*128;
  int tid = threadIdx.x;
  {
    int jh = tid&7;
    float w2c0[32], w2c1[32];
    #pragma unroll
    for(int c=0;c<32;++c){ w2c0[c] = w2[c*16+2*jh]; w2c1[c] = w2[c*16+2*jh+1]; }
    for(int idx=tid; idx<NN*8; idx+=256){
      int m = idx>>3;
      const float4* hp = (const float4*)(h1 + (size_t)(b*NN+m)*32);
      float a0=0.f, a1=0.f;
      #pragma unroll
      for(int q=0;q<8;++q){
        float4 hv = hp[q];
        a0 += hv.x*w2c0[4*q] + hv.y*w2c0[4*q+1] + hv.z*w2c0[4*q+2] + hv.w*w2c0[4*q+3];
        a1 += hv.x*w2c1[4*q] + hv.y*w2c1[4*q+1] + hv.z*w2c1[4*q+2] + hv.w*w2c1[4*q+3];
      }
      t_s[m*16+2*jh] = a0;
      t_s[m*16+2*jh+1] = a1;
    }
  }
  int j = tid&15, nl = tid>>4;
  float acc[8];
  #pragma unroll
  for(int q=0;q<8;++q) acc[q]=0.f;
  for(int mt=0; mt<8; ++mt){
    __syncthreads();
    for(int idx=tid; idx<128*64; idx+=256){
      int r = idx>>6, cc = idx&63;
      adj_s[r*68+cc] = adj[(size_t)(n0+r)*NN + mt*64 + cc];
    }
    __syncthreads();
    for(int mm=0; mm<64; mm+=4){
      float tv[4];
      #pragma unroll
      for(int q=0;q<4;++q) tv[q] = t_s[(mt*64+mm+q)*16 + j];
      #pragma unroll
      for(int q=0;q<8;++q){
        float4 a4 = *(const float4*)&adj_s[(nl+16*q)*68 + mm];
        acc[q] += a4.x*tv[0] + a4.y*tv[1] + a4.z*tv[2] + a4.w*tv[3];
      }
    }
  }
  float bbj = b2[j];
  #pragma unroll
  for(int q=0;q<8;++q){
    int n = n0 + nl + 16*q;
    g[(size_t)(b*NN+n)*16 + j] = fmaxf(acc[q]+bbj, 0.0f);
  }
}

// ---------------- conv1 -> pool -> conv2 ----------------
__global__ __launch_bounds__(256) void k_conv(const float* __restrict__ g, const float* __restrict__ wc1,
        const float* __restrict__ bc1, const float* __restrict__ wc2, const float* __restrict__ bc2,
        float* __restrict__ feat){
  __shared__ float g_s[NN*16];
  __shared__ float w1_s[3*NN*4];
  __shared__ float c1p[4][4][16];
  __shared__ float c1_s[4][16];
  __shared__ float p_s[4][8];
  int b = blockIdx.x, tid = threadIdx.x;
  for(int idx=tid; idx<NN*16; idx+=256) g_s[idx] = g[(size_t)b*NN*16 + idx];
  for(int idx=tid; idx<3*NN*4; idx+=256) w1_s[idx] = wc1[idx];
  __syncthreads();
  {
    int q = tid>>6, p = tid&63, o = p>>4, x = p&15;
    int c0 = q*128;
    float acc = 0.f;
    #pragma unroll
    for(int k=0;k<3;++k){
      int xx = x + k - 1;
      if(xx>=0 && xx<16){
        #pragma unroll 4
        for(int c=c0;c<c0+128;++c) acc += g_s[c*16+xx]*w1_s[(k*NN+c)*4+o];
      }
    }
    c1p[q][o][x] = acc;
  }
  __syncthreads();
  if(tid<64){
    int o = tid>>4, x = tid&15;
    c1_s[o][x] = c1p[0][o][x]+c1p[1][o][x]+c1p[2][o][x]+c1p[3][o][x] + bc1[o];
  }
  __syncthreads();
  if(tid<32){
    int oo = tid>>3, xp = tid&7;
    float pv = 0.5f*(c1_s[oo][2*xp]+c1_s[oo][2*xp+1]);
    p_s[oo][xp] = pv;
    feat[b*192 + 32 + oo*8 + xp] = pv;
  }
  __syncthreads();
  if(tid<32){
    int oo = tid>>3, x2 = tid&7;
    float a2 = bc2[oo];
    #pragma unroll
    for(int k=0;k<3;++k){
      int xx = x2 + k - 1;
      if(xx>=0 && xx<8){
        #pragma unroll
        for(int c=0;c<4;++c) a2 += p_s[c][xx]*wc2[(k*4+c)*4+oo];
      }
    }
    feat[b*192 + oo*8 + x2] = a2;
  }
}

// ---------------- LSTM1: R3 core + 12/20 LDS/L2 weight split ----------------
// thread tid: q=tid&3 (h slice), grp=tid>>2 (cols 4grp..4grp+3); reduced z at col=tid.
// Rows q*32+{0..11} staged in LDS (96KB, lane-contiguous); rows q*32+{12..31} streamed
// from L2 in-loop (R3-validated codegen: __launch_bounds__(512,2), VGPR ~84, no spill).
__global__ __launch_bounds__(512,2) void k_lstm1(const float* __restrict__ in, const float* __restrict__ k1,
        const float* __restrict__ rk1, const float* __restrict__ b1, float* __restrict__ l1){
  __shared__ float4 wlds[6144];     // 96KB: [w*12+k][64 lanes]
  __shared__ float seq_s[HH*FF];
  __shared__ float h_s2[4*36];
  __shared__ float a_s[GD];
  int b = blockIdx.x, tid = threadIdx.x;
  int q = tid&3, grp = tid>>2;
  int w_ = tid>>6, l = tid&63;
  bool q0 = (tid&1)!=0, q1 = (tid&2)!=0;
  const float4* rkp = (const float4*)rk1;
  // stage rows {q*32+k : k<12} -> wlds[(w2*12+k)*64 + jj*4 + qq]  (g-coalesced reads)
  for(int g = tid; g < 6144; g += 512){
    int r = g>>7;              // 0..47
    int qq = r/12, k = r - qq*12;
    int col4 = g&127;
    int w2 = col4>>4, jj = col4&15;
    wlds[(w2*12+k)*64 + jj*4 + qq] = rkp[(size_t)(qq*32+k)*(GD/4) + col4];
  }
  float wkx[FF];
  #pragma unroll
  for(int f=0;f<FF;++f) wkx[f] = k1[f*GD+tid];
  float bz = b1[tid];
  bool isg = ((tid>>7)==2);
  float Ac = isg?1.f:0.f, Bc = isg?-2.f:1.f, Sc = isg?2.f:-1.f;
  for(int idx=tid; idx<HH*FF; idx+=512)
    seq_s[idx] = in[(size_t)(b*HH + (idx>>3))*NN*FF + (idx&7)];
  if(tid<UL) h_s2[(tid>>5)*36 + (tid&31)] = 0.0f;
  float c = 0.0f;
  __syncthreads();
  const float4* hq = (const float4*)&h_s2[q*36];
  const float4* wl = &wlds[(w_*12)*64 + l];
  #pragma unroll 1
  for(int t=0;t<HH;++t){
    // x-projection (broadcast reads)
    float4 x0 = *(const float4*)&seq_s[t*FF];
    float4 x1 = *(const float4*)&seq_s[t*FF+4];
    float zx = bz + x0.x*wkx[0]+x0.y*wkx[1]+x0.z*wkx[2]+x0.w*wkx[3]
                  + x1.x*wkx[4]+x1.y*wkx[5]+x1.z*wkx[6]+x1.w*wkx[7];
    float p0=0.f,p1=0.f,p2=0.f,p3=0.f;
    // LDS half: rows q*32 + 0..11 (conflict-free lane-contiguous b128)
    #pragma unroll
    for(int kk=0;kk<3;++kk){
      float4 hv = hq[kk];
      float4 wa = wl[(4*kk+0)*64];
      float4 wb = wl[(4*kk+1)*64];
      float4 wc = wl[(4*kk+2)*64];
      float4 wd = wl[(4*kk+3)*64];
      p0 += hv.x*wa.x + hv.y*wb.x + hv.z*wc.x + hv.w*wd.x;
      p1 += hv.x*wa.y + hv.y*wb.y + hv.z*wc.y + hv.w*wd.y;
      p2 += hv.x*wa.z + hv.y*wb.z + hv.z*wc.z + hv.w*wd.z;
      p3 += hv.x*wa.w + hv.y*wb.w + hv.z*wc.w + hv.w*wd.w;
    }
    // streamed half: rows q*32 + 12..31 (L2, in-loop loads as in R3)
    #pragma unroll
    for(int kk=0;kk<5;++kk){
      float4 hv = hq[3+kk];
      float4 wa = rkp[(size_t)(q*32+12+4*kk+0)*(GD/4) + grp];
      float4 wb = rkp[(size_t)(q*32+12+4*kk+1)*(GD/4) + grp];
      float4 wc = rkp[(size_t)(q*32+12+4*kk+2)*(GD/4) + grp];
      float4 wd = rkp[(size_t)(q*32+12+4*kk+3)*(GD/4) + grp];
      p0 += hv.x*wa.x + hv.y*wb.x + hv.z*wc.x + hv.w*wd.x;
      p1 += hv.x*wa.y + hv.y*wb.y + hv.z*wc.y + hv.w*wd.y;
      p2 += hv.x*wa.z + hv.y*wb.z + hv.z*wc.z + hv.w*wd.z;
      p3 += hv.x*wa.w + hv.y*wb.w + hv.z*wc.w + hv.w*wd.w;
    }
    // 4-lane transpose-reduce (R3-validated): lane ends with col = tid
    float send0 = q0 ? p0 : p1;
    float send1 = q0 ? p2 : p3;
    float r0 = __shfl_xor(send0, 1);
    float r1 = __shfl_xor(send1, 1);
    float s0 = (q0 ? p1 : p0) + r0;
    float s1v = (q0 ? p3 : p2) + r1;
    float send2 = q1 ? s0 : s1v;
    float r2 = __shfl_xor(send2, 2);
    float z = zx + (q1 ? s1v : s0) + r2;
    float act = Ac + Bc*frcp(1.0f + __expf(Sc*z));
    a_s[tid] = act;
    __syncthreads();
    int u = tid&127;
    float ia=a_s[u], fa=a_s[UL+u], ga=a_s[2*UL+u], oa=a_s[3*UL+u];
    c = fa*c + ia*ga;
    float th = 1.0f - 2.0f*frcp(1.0f + __expf(2.0f*c));
    float hn = oa*th;
    if(tid<UL){
      h_s2[(tid>>5)*36 + (tid&31)] = hn;
      l1[((size_t)b*HH + t)*UL + tid] = hn;
    }
    __syncthreads();
  }
}

// ---------------- zin2 = l1 @ k2 + b2 ----------------
__global__ __launch_bounds__(256) void k_zin2(const float* __restrict__ l1, const float* __restrict__ k2,
        const float* __restrict__ b2, float* __restrict__ zin){
  __shared__ float l_s[21*UL];
  int b = blockIdx.x>>3, t0 = (blockIdx.x&7)*21;
  int tid = threadIdx.x;
  for(int idx=tid; idx<21*UL; idx+=256)
    l_s[idx] = l1[((size_t)b*HH + t0 + (idx>>7))*UL + (idx&127)];
  __syncthreads();
  float acc0[21], acc1[21];
  #pragma unroll
  for(int q=0;q<21;++q){acc0[q]=0.f;acc1[q]=0.f;}
  for(int j=0;j<UL;j+=4){
    float kv00=k2[j*GD+tid],     kv01=k2[(j+1)*GD+tid],     kv02=k2[(j+2)*GD+tid],     kv03=k2[(j+3)*GD+tid];
    float kv10=k2[j*GD+tid+256], kv11=k2[(j+1)*GD+tid+256], kv12=k2[(j+2)*GD+tid+256], kv13=k2[(j+3)*GD+tid+256];
    #pragma unroll
    for(int q=0;q<21;++q){
      float4 lv = *(const float4*)&l_s[q*UL + j];
      acc0[q] += lv.x*kv00 + lv.y*kv01 + lv.z*kv02 + lv.w*kv03;
      acc1[q] += lv.x*kv10 + lv.y*kv11 + lv.z*kv12 + lv.w*kv13;
    }
  }
  float bb0 = b2[tid], bb1 = b2[tid+256];
  #pragma unroll
  for(int q=0;q<21;++q){
    zin[((size_t)b*HH + t0 + q)*GD + tid]       = acc0[q] + bb0;
    zin[((size_t)b*HH + t0 + q)*GD + tid + 256] = acc1[q] + bb1;
  }
}

// ---------------- LSTM2: R3 core + zin prefetch + 12/20 LDS/L2 weight split ----------------
__global__ __launch_bounds__(512,2) void k_lstm2(const float* __restrict__ zin, const float* __restrict__ rk2,
        float* __restrict__ feat){
  __shared__ float4 wlds[6144];     // 96KB
  __shared__ float h_s2[4*36];
  __shared__ float a_s[GD];
  int b = blockIdx.x, tid = threadIdx.x;
  int q = tid&3, grp = tid>>2;
  int w_ = tid>>6, l = tid&63;
  bool q0 = (tid&1)!=0, q1 = (tid&2)!=0;
  const float4* rkp = (const float4*)rk2;
  for(int g = tid; g < 6144; g += 512){
    int r = g>>7;
    int qq = r/12, k = r - qq*12;
    int col4 = g&127;
    int w2 = col4>>4, jj = col4&15;
    wlds[(w2*12+k)*64 + jj*4 + qq] = rkp[(size_t)(qq*32+k)*(GD/4) + col4];
  }
  bool isg = ((tid>>7)==2);
  float Ac = isg?1.f:0.f, Bc = isg?-2.f:1.f, Sc = isg?2.f:-1.f;
  if(tid<UL) h_s2[(tid>>5)*36 + (tid&31)] = 0.0f;
  float c = 0.0f;
  float zc = zin[(size_t)b*HH*GD + tid];
  __syncthreads();
  const float4* hq = (const float4*)&h_s2[q*36];
  const float4* wl = &wlds[(w_*12)*64 + l];
  #pragma unroll 1
  for(int t=0;t<HH;++t){
    float nz = 0.f;
    if(t+1<HH) nz = zin[((size_t)b*HH + t+1)*GD + tid];   // prefetch next step
    float p0=0.f,p1=0.f,p2=0.f,p3=0.f;
    #pragma unroll
    for(int kk=0;kk<3;++kk){
      float4 hv = hq[kk];
      float4 wa = wl[(4*kk+0)*64];
      float4 wb = wl[(4*kk+1)*64];
      float4 wc = wl[(4*kk+2)*64];
      float4 wd = wl[(4*kk+3)*64];
      p0 += hv.x*wa.x + hv.y*wb.x + hv.z*wc.x + hv.w*wd.x;
      p1 += hv.x*wa.y + hv.y*wb.y + hv.z*wc.y + hv.w*wd.y;
      p2 += hv.x*wa.z + hv.y*wb.z + hv.z*wc.z + hv.w*wd.z;
      p3 += hv.x*wa.w + hv.y*wb.w + hv.z*wc.w + hv.w*wd.w;
    }
    #pragma unroll
    for(int kk=0;kk<5;++kk){
      float4 hv = hq[3+kk];
      float4 wa = rkp[(size_t)(q*32+12+4*kk+0)*(GD/4) + grp];
      float4 wb = rkp[(size_t)(q*32+12+4*kk+1)*(GD/4) + grp];
      float4 wc = rkp[(size_t)(q*32+12+4*kk+2)*(GD/4) + grp];
      float4 wd = rkp[(size_t)(q*32+12+4*kk+3)*(GD/4) + grp];
      p0 += hv.x*wa.x + hv.y*wb.x + hv.z*wc.x + hv.w*wd.x;
      p1 += hv.x*wa.y + hv.y*wb.y + hv.z*wc.y + hv.w*wd.y;
      p2 += hv.x*wa.z + hv.y*wb.z + hv.z*wc.z + hv.w*wd.z;
      p3 += hv.x*wa.w + hv.y*wb.w + hv.z*wc.w + hv.w*wd.w;
    }
    float send0 = q0 ? p0 : p1;
    float send1 = q0 ? p2 : p3;
    float r0 = __shfl_xor(send0, 1);
    float r1 = __shfl_xor(send1, 1);
    float s0 = (q0 ? p1 : p0) + r0;
    float s1v = (q0 ? p3 : p2) + r1;
    float send2 = q1 ? s0 : s1v;
    float r2 = __shfl_xor(send2, 2);
    float z = zc + (q1 ? s1v : s0) + r2;
    float act = Ac + Bc*frcp(1.0f + __expf(Sc*z));
    a_s[tid] = act;
    __syncthreads();
    int u = tid&127;
    float ia=a_s[u], fa=a_s[UL+u], ga=a_s[2*UL+u], oa=a_s[3*UL+u];
    c = fa*c + ia*ga;
    float th = 1.0f - 2.0f*frcp(1.0f + __expf(2.0f*c));
    float hn = oa*th;
    if(tid<UL){
      h_s2[(tid>>5)*36 + (tid&31)] = hn;
      if(t==HH-1) feat[b*192 + 64 + tid] = hn;
    }
    __syncthreads();
    zc = nz;
  }
}

// ---------------- final dense ----------------
__global__ __launch_bounds__(256) void k_out(const float* __restrict__ feat, const float* __restrict__ wo,
        const float* __restrict__ bo, float* __restrict__ out){
  int idx = blockIdx.x*256 + threadIdx.x;
  if(idx >= BB*24) return;
  int b = idx/24, p = idx - b*24;
  float a0 = bo[p], a1 = 0.f, a2 = 0.f, a3 = 0.f;
  const float* f = feat + b*192;
  for(int k=0;k<192;k+=4){
    a0 += f[k]*wo[k*24+p];
    a1 += f[k+1]*wo[(k+1)*24+p];
    a2 += f[k+2]*wo[(k+2)*24+p];
    a3 += f[k+3]*wo[(k+3)*24+p];
  }
  out[idx] = (a0+a1)+(a2+a3);
}

extern "C" void kernel_launch(void* const* d_in, const int* in_sizes, int n_in,
                              void* d_out, int out_size, void* d_ws, size_t ws_size,
                              hipStream_t stream){
  const float* inp = (const float*)d_in[0];
  const float* adj = (const float*)d_in[1];
  const float* w1  = (const float*)d_in[2];
  const float* b1  = (const float*)d_in[3];
  const float* w2  = (const float*)d_in[4];
  const float* b2  = (const float*)d_in[5];
  const float* wc1 = (const float*)d_in[6];
  const float* bc1 = (const float*)d_in[7];
  const float* wc2 = (const float*)d_in[8];
  const float* bc2 = (const float*)d_in[9];
  const float* k1  = (const float*)d_in[10];
  const float* rk1 = (const float*)d_in[11];
  const float* bl1 = (const float*)d_in[12];
  const float* k2  = (const float*)d_in[13];
  const float* rk2 = (const float*)d_in[14];
  const float* bl2 = (const float*)d_in[15];
  const float* wo  = (const float*)d_in[16];
  const float* bo  = (const float*)d_in[17];
  float* out = (float*)d_out;
  float* ws = (float*)d_ws;

  float* ps   = ws;                 // 524288
  float* nf   = ps + 524288;        // 229376
  float* h1   = nf + 229376;        // 1048576
  float* g    = h1 + 1048576;       // 524288
  float* feat = g  + 524288;        // 12288
  float* l1   = feat + 12288;       // 1376256
  float* zin  = l1 + 1376256;       // 5505024

  k_sum  <<<dim3(256), dim3(256), 0, stream>>>(inp, ps);
  k_sumc <<<dim3(128), dim3(256), 0, stream>>>(ps, nf);
  k_gcn1 <<<dim3(256), dim3(256), 0, stream>>>(nf, adj, w1, b1, h1);
  k_gcn2 <<<dim3(256), dim3(256), 0, stream>>>(h1, adj, w2, b2, g);
  k_conv <<<dim3(64),  dim3(256), 0, stream>>>(g, wc1, bc1, wc2, bc2, feat);
  k_lstm1<<<dim3(64),  dim3(512), 0, stream>>>(inp, k1, rk1, bl1, l1);
  k_zin2 <<<dim3(512), dim3(256), 0, stream>>>(l1, k2, bl2, zin);
  k_lstm2<<<dim3(64),  dim3(512), 0, stream>>>(zin, rk2, feat);
  k_out  <<<dim3(6),   dim3(256), 0, stream>>>(feat, wo, bo, out);
}